// Round 15
// baseline (525.027 us; speedup 1.0000x reference)
//
#include <hip/hip_runtime.h>
#include <float.h>

#define LRELU(v) ((v) > 0.0f ? (v) : 0.01f * (v))

// Order-preserving float->int map (involution): a<b  <=>  f2ord(a)<f2ord(b)
// Finite floats map below 0x7F800001; 0x7FFFFFFF is unreachable -> sentinel.
__device__ __forceinline__ int f2ord(float f) {
    int i = __float_as_int(f);
    return (i >= 0) ? i : (int)(0x80000000u - (unsigned int)i);
}
__device__ __forceinline__ float ord2f(int m) {
    int i = (m >= 0) ? m : (int)(0x80000000u - (unsigned int)m);
    return __int_as_float(i);
}

// ---------------- prep: edge append ONLY ----------------
// Input linears are never materialized: conv computes them at point-of-use
// from raw inputs (x_f 2.56MB, x_e 7.7MB, x_v 1.9MB — L2-resident; R11
// measured FETCH 159->63MB). Sharded bucket append — buckets = 32
// consecutive dst nodes, 8 shards/bucket x 64 slots. Shard by edge index
// (idx&7) keeps per-cursor atomic chains ~Poisson(24) worst (R5 lesson:
// 180-400-deep chains = 156us death). Slot packs (src<<5)|(dst&31).
//   g: 0=F2E 1=E2V 2=FF 3=E2F 4=V2E
//   E:       160000,160000,240000,160000,160000 (total 880000)
//   buckets: 2500,1250,1250,1250,2500  bOff: 0,2500,3750,5000,6250 (tot 8750)
__global__ void prep(const int* __restrict__ e0, const int* __restrict__ e1,
                     const int* __restrict__ e2, const int* __restrict__ e3,
                     const int* __restrict__ e4, int* __restrict__ cur,
                     int* __restrict__ slots) {
    int idx = blockIdx.x * 256 + threadIdx.x;
    if (idx >= 880000) return;
    const int cum[6]  = {0, 160000, 320000, 560000, 720000, 880000};
    const int bOff[5] = {0, 2500, 3750, 5000, 6250};
    const int Eg[5]   = {160000, 160000, 240000, 160000, 160000};
    const int* eds[5] = {e0, e1, e2, e3, e4};
    int g = 0;
#pragma unroll
    for (int k = 1; k < 5; ++k) g += (idx >= cum[k]);
    int e = idx - cum[g];
    int s = eds[g][e];
    int d = eds[g][Eg[g] + e];
    int cbase = (bOff[g] + (d >> 5)) * 8 + (idx & 7);
    int c = atomicAdd(&cur[cbase], 1);
    if (c < 64) slots[(size_t)cbase * 64 + c] = (s << 5) | (d & 31);
}

// ---------------- fused conv ----------------
struct ConvJob {
    const float* xsrc; const float* xdst;     // materialized paths (cin==0)
    const int* cur; int* slots;               // shard cursors + slot pool
    const float* W; const float* bias; float* out;
    const float* sraw; const float* sW; const float* sb; int scin; // src-inline
    const float* draw; const float* dW; const float* db; int dcin; // dst-inline
    int Ns; int Nd; int blkStart;
};
struct ConvJobs { ConvJob e[3]; };

// 32 dst nodes / block of 256 threads. TWO barriers total.
// SHARD PADDING (R15): threads t<64 pad the block's own 8 shards to a
// multiple of 8 by duplicating slot[0] (a REAL edge of this bucket —
// atomicMin idempotent, so re-minning it is a no-op). Runs concurrently
// with smxi init; the existing __syncthreads (vmcnt drain + same-CU L1)
// makes the writes visible block-locally. Each shard is mutated+read by
// exactly ONE block; pad is idempotent across graph replays. Phase-1 loops
// are then fully BRANCHLESS (no tail clamp selects — 7 cmp+cndmask chains
// per 8 slots removed, all serially dependent on the slot-word load).
// VGPR CLIFF (R13/R14): waves/CU halve at VGPR=64; R14 landed exactly 64
// via bias-after-min -> 39% occ. NEVER force the tier with launch_bounds
// (R13: forced 32 -> total scratch spill, 855MB writes, 431us).
// BIAS-AFTER-MIN + MIN-BEFORE-LRELU (R12/R14, verified): bias is
// edge-invariant and lrelu strictly monotone -> min_e lrelu(Wx_e+b)
// = lrelu(min_e(Wx_e) + b). Inline paths min raw W·x; phase 2 applies
// +sb and lrelu once per (node,ch). scin==0 sources are final features.
// Phase 1: 8 edge-lane groups (32 threads, one (b,c4) per lane); group el
//          walks shard el.
//          scin==0: 8-deep float4 gather of materialized 128B rows.
//          scin==4: 8-deep float4 raw gather (16B rows) + FMA tree.
//          scin==6: 4-deep, 3x float2 raw loads (24B rows alternate 16B/8B
//                   alignment — float4 unsafe) + FMA tree.
//          smxi row stride 33 ints: bank = (4*dl+b+4*c4+i)%32 ->
//          conflict-free (measured 0).
// Phase 2: one h-row per lane (wave w: rows (w&1)*64+lane, channel half
//          (w>>1)*16, wave-uniform via readfirstlane). Residual from xd
//          registers. Empty nodes keep the 0x7FFFFFFF sentinel.
__global__ __launch_bounds__(256, 1)
void conv_fused(ConvJobs jobs) {
    __shared__ int smxi[128][33];   // [node_local*4+b][c] f2ord mins; 132B rows
    int t = threadIdx.x;
    int bid = blockIdx.x;
    int g = (bid >= jobs.e[2].blkStart) ? 2 : (bid >= jobs.e[1].blkStart) ? 1 : 0;
    const float* xsrc  = jobs.e[g].xsrc;
    const float* xdst  = jobs.e[g].xdst;
    const int*   cur   = jobs.e[g].cur;
    int*         slots = jobs.e[g].slots;
    const float* W     = jobs.e[g].W;
    const float* bias  = jobs.e[g].bias;
    float*       out   = jobs.e[g].out;
    const float* sraw  = jobs.e[g].sraw;
    const float* sW    = jobs.e[g].sW;
    const float* sb    = jobs.e[g].sb;
    int scin           = jobs.e[g].scin;
    const float* draw  = jobs.e[g].draw;
    const float* dW    = jobs.e[g].dW;
    const float* db    = jobs.e[g].db;
    int dcin           = jobs.e[g].dcin;
    int Ns = jobs.e[g].Ns, Nd = jobs.e[g].Nd;
    int lb = bid - jobs.e[g].blkStart;
    int base = lb * 32;

    // pad own 8 shards to x8 with slot[0] dups (branchless hot loop below)
    if (t < 64) {
        int sh = t >> 3, k = t & 7;
        int L = cur[lb * 8 + sh]; L = L > 64 ? 64 : L;
        int Lp = (L + 7) & ~7;
        int* sp = slots + (size_t)(lb * 8 + sh) * 64;
        int pos = L + k;
        if (L > 0 && pos < Lp) sp[pos] = sp[0];
    }
    for (int i = t; i < 128 * 33; i += 256) ((int*)smxi)[i] = 0x7FFFFFFF;
    __syncthreads();

    // phase 0: phase-2 row mapping + xd (load or inline-compute)
    int w    = t >> 6;
    int lane = t & 63;
    int r    = (w & 1) * 64 + lane;                       // h-row 0..127
    int c0   = __builtin_amdgcn_readfirstlane((w >> 1) * 16);  // wave-uniform
    int nl = r >> 2, b2 = r & 3;
    int d  = base + nl;
    float xd[32];
    if (dcin > 0) {
        // xd = lrelu(draw_row @ dW + db); dW/db loads are uniform
#pragma unroll
        for (int c = 0; c < 32; ++c) xd[c] = db[c];
        const float* xrp = draw + ((size_t)b2 * Nd + d) * dcin;
        for (int k = 0; k < dcin; ++k) {
            float xrk = xrp[k];
            const float* wk = dW + k * 32;
#pragma unroll
            for (int c = 0; c < 32; ++c) xd[c] = fmaf(xrk, wk[c], xd[c]);
        }
#pragma unroll
        for (int c = 0; c < 32; ++c) xd[c] = LRELU(xd[c]);
    } else {
        const float* xdp = xdst + ((size_t)b2 * Nd + d) * 32;
#pragma unroll
        for (int q = 0; q < 8; ++q) {
            float4 v = ((const float4*)xdp)[q];
            xd[4*q] = v.x; xd[4*q+1] = v.y; xd[4*q+2] = v.z; xd[4*q+3] = v.w;
        }
    }

    // phase 1: shard-per-group pipelined gathers + LDS atomic min (branchless)
    {
        int c4 = t & 7;            // channel quad
        int b  = (t >> 3) & 3;
        int el = t >> 5;           // shard id 0..7
        int len = cur[lb * 8 + el];
        len = len > 64 ? 64 : len;
        len = (len + 7) & ~7;      // padded region holds slot[0] dups
        const int* ce = slots + (size_t)(lb * 8 + el) * 64;
        if (scin == 0) {
            const float* xsb = xsrc + (size_t)b * Ns * 32 + c4 * 4;
            for (int j = 0; j < len; j += 8) {
                int4 sw0 = *(const int4*)(ce + j);
                int4 sw1 = *(const int4*)(ce + j + 4);
                float4 v0 = *(const float4*)(xsb + (size_t)(sw0.x & ~31));
                float4 v1 = *(const float4*)(xsb + (size_t)(sw0.y & ~31));
                float4 v2 = *(const float4*)(xsb + (size_t)(sw0.z & ~31));
                float4 v3 = *(const float4*)(xsb + (size_t)(sw0.w & ~31));
                float4 v4 = *(const float4*)(xsb + (size_t)(sw1.x & ~31));
                float4 v5 = *(const float4*)(xsb + (size_t)(sw1.y & ~31));
                float4 v6 = *(const float4*)(xsb + (size_t)(sw1.z & ~31));
                float4 v7 = *(const float4*)(xsb + (size_t)(sw1.w & ~31));
#define MINGRP(se, v)  { int* mr = &smxi[((se) & 31) * 4 + b][c4 * 4]; \
                atomicMin(&mr[0], f2ord((v).x)); atomicMin(&mr[1], f2ord((v).y)); \
                atomicMin(&mr[2], f2ord((v).z)); atomicMin(&mr[3], f2ord((v).w)); }
                MINGRP(sw0.x, v0) MINGRP(sw0.y, v1) MINGRP(sw0.z, v2) MINGRP(sw0.w, v3)
                MINGRP(sw1.x, v4) MINGRP(sw1.y, v5) MINGRP(sw1.z, v6) MINGRP(sw1.w, v7)
            }
        } else if (scin == 4) {
            const float* xr = sraw + (size_t)b * Ns * 4;
            float4 w0 = *(const float4*)(sW +  0 + c4 * 4);
            float4 w1 = *(const float4*)(sW + 32 + c4 * 4);
            float4 w2 = *(const float4*)(sW + 64 + c4 * 4);
            float4 w3 = *(const float4*)(sW + 96 + c4 * 4);
            for (int j = 0; j < len; j += 8) {
                int4 sw0 = *(const int4*)(ce + j);
                int4 sw1 = *(const int4*)(ce + j + 4);
                float4 r0 = *(const float4*)(xr + (size_t)(sw0.x >> 5) * 4);
                float4 r1 = *(const float4*)(xr + (size_t)(sw0.y >> 5) * 4);
                float4 r2 = *(const float4*)(xr + (size_t)(sw0.z >> 5) * 4);
                float4 r3 = *(const float4*)(xr + (size_t)(sw0.w >> 5) * 4);
                float4 r4 = *(const float4*)(xr + (size_t)(sw1.x >> 5) * 4);
                float4 r5 = *(const float4*)(xr + (size_t)(sw1.y >> 5) * 4);
                float4 r6 = *(const float4*)(xr + (size_t)(sw1.z >> 5) * 4);
                float4 r7 = *(const float4*)(xr + (size_t)(sw1.w >> 5) * 4);
// pre-bias pre-activation min (bias edge-invariant, lrelu monotone ->
// both applied once in phase 2)
#define CMIN4(se, rr) { \
    float vx = fmaf((rr).w, w3.x, fmaf((rr).z, w2.x, fmaf((rr).y, w1.x, (rr).x * w0.x))); \
    float vy = fmaf((rr).w, w3.y, fmaf((rr).z, w2.y, fmaf((rr).y, w1.y, (rr).x * w0.y))); \
    float vz = fmaf((rr).w, w3.z, fmaf((rr).z, w2.z, fmaf((rr).y, w1.z, (rr).x * w0.z))); \
    float vw = fmaf((rr).w, w3.w, fmaf((rr).z, w2.w, fmaf((rr).y, w1.w, (rr).x * w0.w))); \
    int* mr = &smxi[((se) & 31) * 4 + b][c4 * 4]; \
    atomicMin(&mr[0], f2ord(vx)); atomicMin(&mr[1], f2ord(vy)); \
    atomicMin(&mr[2], f2ord(vz)); atomicMin(&mr[3], f2ord(vw)); }
                CMIN4(sw0.x, r0) CMIN4(sw0.y, r1) CMIN4(sw0.z, r2) CMIN4(sw0.w, r3)
                CMIN4(sw1.x, r4) CMIN4(sw1.y, r5) CMIN4(sw1.z, r6) CMIN4(sw1.w, r7)
            }
        } else {   // scin == 6, 4-deep (payload 24 regs), branchless
            const float* xr = sraw + (size_t)b * Ns * 6;
            float4 w0 = *(const float4*)(sW +   0 + c4 * 4);
            float4 w1 = *(const float4*)(sW +  32 + c4 * 4);
            float4 w2 = *(const float4*)(sW +  64 + c4 * 4);
            float4 w3 = *(const float4*)(sW +  96 + c4 * 4);
            float4 w4 = *(const float4*)(sW + 128 + c4 * 4);
            float4 w5 = *(const float4*)(sW + 160 + c4 * 4);
            for (int j = 0; j < len; j += 4) {
                int4 sw0 = *(const int4*)(ce + j);
                const float* p0 = xr + (size_t)(sw0.x >> 5) * 6;
                const float* p1 = xr + (size_t)(sw0.y >> 5) * 6;
                const float* p2 = xr + (size_t)(sw0.z >> 5) * 6;
                const float* p3 = xr + (size_t)(sw0.w >> 5) * 6;
                float2 a0 = *(const float2*)p0, m0 = *(const float2*)(p0 + 2), z0 = *(const float2*)(p0 + 4);
                float2 a1 = *(const float2*)p1, m1 = *(const float2*)(p1 + 2), z1 = *(const float2*)(p1 + 4);
                float2 a2 = *(const float2*)p2, m2 = *(const float2*)(p2 + 2), z2 = *(const float2*)(p2 + 4);
                float2 a3 = *(const float2*)p3, m3 = *(const float2*)(p3 + 2), z3 = *(const float2*)(p3 + 4);
#define CMIN6(se, A, M, Z) { \
    float vx = fmaf((Z).y, w5.x, fmaf((Z).x, w4.x, fmaf((M).y, w3.x, fmaf((M).x, w2.x, fmaf((A).y, w1.x, (A).x * w0.x))))); \
    float vy = fmaf((Z).y, w5.y, fmaf((Z).x, w4.y, fmaf((M).y, w3.y, fmaf((M).x, w2.y, fmaf((A).y, w1.y, (A).x * w0.y))))); \
    float vz = fmaf((Z).y, w5.z, fmaf((Z).x, w4.z, fmaf((M).y, w3.z, fmaf((M).x, w2.z, fmaf((A).y, w1.z, (A).x * w0.z))))); \
    float vw = fmaf((Z).y, w5.w, fmaf((Z).x, w4.w, fmaf((M).y, w3.w, fmaf((M).x, w2.w, fmaf((A).y, w1.w, (A).x * w0.w))))); \
    int* mr = &smxi[((se) & 31) * 4 + b][c4 * 4]; \
    atomicMin(&mr[0], f2ord(vx)); atomicMin(&mr[1], f2ord(vy)); \
    atomicMin(&mr[2], f2ord(vz)); atomicMin(&mr[3], f2ord(vw)); }
                CMIN6(sw0.x, a0, m0, z0) CMIN6(sw0.y, a1, m1, z1)
                CMIN6(sw0.z, a2, m2, z2) CMIN6(sw0.w, a3, m3, z3)
            }
        }
    }
    __syncthreads();

    // phase 2: out = xd + lrelu([xd|mx] @ W + bias)
    bool has = (smxi[r][0] != 0x7FFFFFFF);   // per-node all-or-nothing
    bool post = (scin != 0);                 // inline paths minned pre-bias/act
    float mx[32];
#pragma unroll
    for (int q = 0; q < 32; ++q) {
        float v = ord2f(smxi[r][q]);
        if (post) { v = v + sb[q]; v = LRELU(v); }   // sb[q] uniform -> s_load
        mx[q] = has ? (xd[q] - v) : 0.0f;
    }
    const float* Wc = W + c0;
    float acc[16];
#pragma unroll
    for (int jj = 0; jj < 16; ++jj) acc[jj] = bias[c0 + jj];
#pragma unroll
    for (int k = 0; k < 64; ++k) {
        float hk = (k < 32) ? xd[k] : mx[k - 32];   // resolved at unroll time
        const float4* wr = (const float4*)(Wc + k * 32);
        float4 q0 = wr[0], q1 = wr[1], q2 = wr[2], q3 = wr[3];
        acc[0]  = fmaf(hk, q0.x, acc[0]);  acc[1]  = fmaf(hk, q0.y, acc[1]);
        acc[2]  = fmaf(hk, q0.z, acc[2]);  acc[3]  = fmaf(hk, q0.w, acc[3]);
        acc[4]  = fmaf(hk, q1.x, acc[4]);  acc[5]  = fmaf(hk, q1.y, acc[5]);
        acc[6]  = fmaf(hk, q1.z, acc[6]);  acc[7]  = fmaf(hk, q1.w, acc[7]);
        acc[8]  = fmaf(hk, q2.x, acc[8]);  acc[9]  = fmaf(hk, q2.y, acc[9]);
        acc[10] = fmaf(hk, q2.z, acc[10]); acc[11] = fmaf(hk, q2.w, acc[11]);
        acc[12] = fmaf(hk, q3.x, acc[12]); acc[13] = fmaf(hk, q3.y, acc[13]);
        acc[14] = fmaf(hk, q3.z, acc[14]); acc[15] = fmaf(hk, q3.w, acc[15]);
    }
    // residual from registers (c0 is wave-uniform 0 or 16)
    float xr2[16];
#pragma unroll
    for (int i = 0; i < 16; ++i) xr2[i] = (c0 == 0) ? xd[i] : xd[16 + i];
    float* op = out + ((size_t)b2 * Nd + d) * 32 + c0;
#pragma unroll
    for (int q = 0; q < 4; ++q) {
        float4 o;
        float a0 = acc[4*q], a1 = acc[4*q+1], a2 = acc[4*q+2], a3 = acc[4*q+3];
        o.x = xr2[4*q]   + LRELU(a0); o.y = xr2[4*q+1] + LRELU(a1);
        o.z = xr2[4*q+2] + LRELU(a2); o.w = xr2[4*q+3] + LRELU(a3);
        ((float4*)op)[q] = o;
    }
}

extern "C" void kernel_launch(void* const* d_in, const int* in_sizes, int n_in,
                              void* d_out, int out_size, void* d_ws, size_t ws_size,
                              hipStream_t stream) {
    const float* x_f = (const float*)d_in[0];
    const float* x_e = (const float*)d_in[1];
    const float* x_v = (const float*)d_in[2];
    // d_in[3] = index_id (identity arange) — unused
    const int* fe = (const int*)d_in[4];
    const int* ev = (const int*)d_in[5];
    const int* ff = (const int*)d_in[6];
    const int* ef = (const int*)d_in[7];
    const int* ve = (const int*)d_in[8];
    const float* Wf = (const float*)d_in[9];
    const float* bf = (const float*)d_in[10];
    const float* We = (const float*)d_in[11];
    const float* be = (const float*)d_in[12];
    const float* Wv = (const float*)d_in[13];
    const float* bv = (const float*)d_in[14];
    const float* W_f2e = (const float*)d_in[15];
    const float* b_f2e = (const float*)d_in[16];
    const float* W_e2v = (const float*)d_in[17];
    const float* b_e2v = (const float*)d_in[18];
    const float* W_ff  = (const float*)d_in[19];
    const float* b_ff  = (const float*)d_in[20];
    const float* W_e2f = (const float*)d_in[21];
    const float* b_e2f = (const float*)d_in[22];
    const float* W_v2e = (const float*)d_in[23];
    const float* b_v2e = (const float*)d_in[24];

    const int B = 4, Nf = 40000, Ne = 80000, Nv = 40000;
    const int NFC = B * Nf * 32;
    const int NEC = B * Ne * 32;
    const int CUR_TOTAL = 70016;            // 8750*8 cursors (padded)
    const int SLOT_TOTAL = 8750 * 512;      // 8 shards * 64 slots per bucket
    const int INT_WORDS = CUR_TOTAL + SLOT_TOTAL;

    float* oxf = (float*)d_out;        // xf1 then final xf
    float* oxe = oxf + NFC;            // final xe
    float* oxv = oxe + NEC;            // final xv (written once, by E2V)

    // Plan A (merged epilogue) routes xe1 through ws so E2F and V2E can run
    // in ONE dispatch (removes the xe1 read/overwrite anti-dependence).
    size_t needA = (size_t)NEC * 4 + (size_t)INT_WORDS * 4;
    bool merged = ws_size >= needA;

    float* ws  = (float*)d_ws;
    float* xe1 = merged ? ws : oxe;    // where F2E writes xe1
    // int area: cur[70016] | slots[4480000]
    int* cur   = (int*)(merged ? (ws + NEC) : ws);
    int* slots = cur + CUR_TOTAL;

    // zero append cursors (280 KB, stream-ordered, graph-capture-safe)
    hipMemsetAsync(cur, 0, (size_t)CUR_TOTAL * 4, stream);

    // edge-append only (no linear stage — convs inline it at point of use)
    prep<<<3438, 256, 0, stream>>>(fe, ev, ff, ef, ve, cur, slots);

    // per-graph cursor/slot pointers (buckets: 2500,1250,1250,1250,2500)
    const int* cu_f2e = cur;            int* sl_f2e = slots;
    const int* cu_e2v = cur + 2500*8;   int* sl_e2v = slots + (size_t)2500*512;
    const int* cu_ff  = cur + 3750*8;   int* sl_ff  = slots + (size_t)3750*512;
    const int* cu_e2f = cur + 5000*8;   int* sl_e2f = slots + (size_t)5000*512;
    const int* cu_v2e = cur + 6250*8;   int* sl_v2e = slots + (size_t)6250*512;

    // Launch 1: F2E + E2V + FF (mutually independent), 32 nodes/block.
    // All src and dst linears computed inline from raw inputs.
    {
        ConvJobs j;
        j.e[0] = {nullptr, nullptr, cu_f2e, sl_f2e, W_f2e, b_f2e, xe1,
                  x_f, Wf, bf, 4,  x_e, We, be, 6,  Nf, Ne, 0};
        j.e[1] = {nullptr, nullptr, cu_e2v, sl_e2v, W_e2v, b_e2v, oxv,
                  x_e, We, be, 6,  x_v, Wv, bv, 3,  Ne, Nv, 2500};
        j.e[2] = {nullptr, nullptr, cu_ff,  sl_ff,  W_ff,  b_ff,  oxf,
                  x_f, Wf, bf, 4,  x_f, Wf, bf, 4,  Nf, Nf, 3750};
        conv_fused<<<5000, 256, 0, stream>>>(j);
    }
    if (merged) {
        // Launch 2: E2F (1250) + V2E (2500) in one dispatch, materialized IO.
        ConvJobs j;
        j.e[0] = {xe1, oxf, cu_e2f, sl_e2f, W_e2f, b_e2f, oxf,
                  nullptr, nullptr, nullptr, 0, nullptr, nullptr, nullptr, 0,
                  Ne, Nf, 0};
        j.e[1] = {oxv, xe1, cu_v2e, sl_v2e, W_v2e, b_v2e, oxe,
                  nullptr, nullptr, nullptr, 0, nullptr, nullptr, nullptr, 0,
                  Nv, Ne, 1250};
        j.e[2] = j.e[0]; j.e[2].blkStart = 0x7FFFFFFF;
        conv_fused<<<3750, 256, 0, stream>>>(j);
    } else {
        // Plan B: serialized epilogue (xe1 lives in oxe, in-place V2E)
        {
            ConvJobs j;
            j.e[0] = {oxe, oxf, cu_e2f, sl_e2f, W_e2f, b_e2f, oxf,
                      nullptr, nullptr, nullptr, 0, nullptr, nullptr, nullptr, 0,
                      Ne, Nf, 0};
            j.e[1] = j.e[0]; j.e[1].blkStart = 0x7FFFFFFF;
            j.e[2] = j.e[0]; j.e[2].blkStart = 0x7FFFFFFF;
            conv_fused<<<1250, 256, 0, stream>>>(j);
        }
        {
            ConvJobs j;
            j.e[0] = {oxv, oxe, cu_v2e, sl_v2e, W_v2e, b_v2e, oxe,
                      nullptr, nullptr, nullptr, 0, nullptr, nullptr, nullptr, 0,
                      Nv, Ne, 0};
            j.e[1] = j.e[0]; j.e[1].blkStart = 0x7FFFFFFF;
            j.e[2] = j.e[0]; j.e[2].blkStart = 0x7FFFFFFF;
            conv_fused<<<2500, 256, 0, stream>>>(j);
        }
    }
}

// Round 16
// 344.923 us; speedup vs baseline: 1.5222x; 1.5222x over previous
//
#include <hip/hip_runtime.h>
#include <float.h>

#define LRELU(v) ((v) > 0.0f ? (v) : 0.01f * (v))

// Order-preserving float->int map (involution): a<b  <=>  f2ord(a)<f2ord(b)
// Finite floats map below 0x7F800001; 0x7FFFFFFF is unreachable -> sentinel.
__device__ __forceinline__ int f2ord(float f) {
    int i = __float_as_int(f);
    return (i >= 0) ? i : (int)(0x80000000u - (unsigned int)i);
}
__device__ __forceinline__ float ord2f(int m) {
    int i = (m >= 0) ? m : (int)(0x80000000u - (unsigned int)m);
    return __int_as_float(i);
}

// ---------------- prep: edge append ONLY ----------------
// Input linears are never materialized: conv computes them at point-of-use
// from raw inputs (x_f 2.56MB, x_e 7.7MB, x_v 1.9MB — L2-resident; R11
// measured FETCH 159->63MB). Sharded bucket append — buckets = 32
// consecutive dst nodes, 8 shards/bucket x 64 slots. Shard by edge index
// (idx&7) keeps per-cursor atomic chains ~Poisson(24) worst (R5 lesson:
// 180-400-deep chains = 156us death). Slot packs (src<<5)|(dst&31).
//   g: 0=F2E 1=E2V 2=FF 3=E2F 4=V2E
//   E:       160000,160000,240000,160000,160000 (total 880000)
//   buckets: 2500,1250,1250,1250,2500  bOff: 0,2500,3750,5000,6250 (tot 8750)
__global__ void prep(const int* __restrict__ e0, const int* __restrict__ e1,
                     const int* __restrict__ e2, const int* __restrict__ e3,
                     const int* __restrict__ e4, int* __restrict__ cur,
                     int* __restrict__ slots) {
    int idx = blockIdx.x * 256 + threadIdx.x;
    if (idx >= 880000) return;
    const int cum[6]  = {0, 160000, 320000, 560000, 720000, 880000};
    const int bOff[5] = {0, 2500, 3750, 5000, 6250};
    const int Eg[5]   = {160000, 160000, 240000, 160000, 160000};
    const int* eds[5] = {e0, e1, e2, e3, e4};
    int g = 0;
#pragma unroll
    for (int k = 1; k < 5; ++k) g += (idx >= cum[k]);
    int e = idx - cum[g];
    int s = eds[g][e];
    int d = eds[g][Eg[g] + e];
    int cbase = (bOff[g] + (d >> 5)) * 8 + (idx & 7);
    int c = atomicAdd(&cur[cbase], 1);
    if (c < 64) slots[(size_t)cbase * 64 + c] = (s << 5) | (d & 31);
}

// ---------------- fused conv ----------------
struct ConvJob {
    const float* xsrc; const float* xdst;     // materialized paths (cin==0)
    const int* cur; const int* slots;         // shard cursors + slot pool
    const float* W; const float* bias; float* out;
    const float* sraw; const float* sW; const float* sb; int scin; // src-inline
    const float* draw; const float* dW; const float* db; int dcin; // dst-inline
    int Ns; int Nd; int blkStart;
};
struct ConvJobs { ConvJob e[3]; };

// 32 dst nodes / block of 256 threads. TWO barriers total.
// R16 = exact revert to R14 (best measured: 339us, VGPR 64, occ 39%).
// R15 LESSON: in-kernel shard padding (write-then-read of slots) stripped
// const-ness -> aliasing killed load batching (VALU 27%, conv1 215us) and
// +8 VGPR re-crossed the cliff. Hot-loop input pointers stay const; the
// tail-clamp selects stay (they were never the bottleneck).
// VGPR CLIFF (R13/R14): waves/CU halve at VGPR=64. R14 landed exactly 64
// via bias-after-min -> 39% occ. NEVER force the tier with launch_bounds
// (R13: forced 32 -> total scratch spill, 855MB writes, 431us).
// BIAS-AFTER-MIN + MIN-BEFORE-LRELU (R12/R14, verified): bias is
// edge-invariant and lrelu strictly monotone -> min_e lrelu(Wx_e+b)
// = lrelu(min_e(Wx_e) + b). Inline paths min raw W·x; phase 2 applies
// +sb and lrelu once per (node,ch). scin==0 sources are final features.
// Phase 1: 8 edge-lane groups (32 threads, one (b,c4) per lane); group el
//          walks shard el.
//          scin==0: 8-deep float4 gather of materialized 128B rows.
//          scin==4: 8-deep float4 raw gather (16B rows) + FMA tree.
//          scin==6: 4-deep, 3x float2 raw loads (24B rows alternate 16B/8B
//                   alignment — float4 unsafe) + FMA tree.
//          Tail slots clamp to slot 0; atomicMin idempotent. smxi row stride
//          33 ints: bank = (4*dl+b+4*c4+i)%32 -> conflict-free (measured 0).
// Phase 2: one h-row per lane (wave w: rows (w&1)*64+lane, channel half
//          (w>>1)*16, wave-uniform via readfirstlane). Residual from xd
//          registers. Empty nodes keep the 0x7FFFFFFF sentinel.
__global__ __launch_bounds__(256, 1)
void conv_fused(ConvJobs jobs) {
    __shared__ int smxi[128][33];   // [node_local*4+b][c] f2ord mins; 132B rows
    int t = threadIdx.x;
    int bid = blockIdx.x;
    int g = (bid >= jobs.e[2].blkStart) ? 2 : (bid >= jobs.e[1].blkStart) ? 1 : 0;
    const float* xsrc  = jobs.e[g].xsrc;
    const float* xdst  = jobs.e[g].xdst;
    const int*   cur   = jobs.e[g].cur;
    const int*   slots = jobs.e[g].slots;
    const float* W     = jobs.e[g].W;
    const float* bias  = jobs.e[g].bias;
    float*       out   = jobs.e[g].out;
    const float* sraw  = jobs.e[g].sraw;
    const float* sW    = jobs.e[g].sW;
    const float* sb    = jobs.e[g].sb;
    int scin           = jobs.e[g].scin;
    const float* draw  = jobs.e[g].draw;
    const float* dW    = jobs.e[g].dW;
    const float* db    = jobs.e[g].db;
    int dcin           = jobs.e[g].dcin;
    int Ns = jobs.e[g].Ns, Nd = jobs.e[g].Nd;
    int lb = bid - jobs.e[g].blkStart;
    int base = lb * 32;

    for (int i = t; i < 128 * 33; i += 256) ((int*)smxi)[i] = 0x7FFFFFFF;
    __syncthreads();

    // phase 0: phase-2 row mapping + xd (load or inline-compute)
    int w    = t >> 6;
    int lane = t & 63;
    int r    = (w & 1) * 64 + lane;                       // h-row 0..127
    int c0   = __builtin_amdgcn_readfirstlane((w >> 1) * 16);  // wave-uniform
    int nl = r >> 2, b2 = r & 3;
    int d  = base + nl;
    float xd[32];
    if (dcin > 0) {
        // xd = lrelu(draw_row @ dW + db); dW/db loads are uniform
#pragma unroll
        for (int c = 0; c < 32; ++c) xd[c] = db[c];
        const float* xrp = draw + ((size_t)b2 * Nd + d) * dcin;
        for (int k = 0; k < dcin; ++k) {
            float xrk = xrp[k];
            const float* wk = dW + k * 32;
#pragma unroll
            for (int c = 0; c < 32; ++c) xd[c] = fmaf(xrk, wk[c], xd[c]);
        }
#pragma unroll
        for (int c = 0; c < 32; ++c) xd[c] = LRELU(xd[c]);
    } else {
        const float* xdp = xdst + ((size_t)b2 * Nd + d) * 32;
#pragma unroll
        for (int q = 0; q < 8; ++q) {
            float4 v = ((const float4*)xdp)[q];
            xd[4*q] = v.x; xd[4*q+1] = v.y; xd[4*q+2] = v.z; xd[4*q+3] = v.w;
        }
    }

    // phase 1: shard-per-group pipelined gathers + LDS atomic min
    {
        int c4 = t & 7;            // channel quad
        int b  = (t >> 3) & 3;
        int el = t >> 5;           // shard id 0..7
        int len = cur[lb * 8 + el];
        len = len > 64 ? 64 : len;
        const int* ce = slots + (size_t)(lb * 8 + el) * 64;
        if (scin == 0) {
            const float* xsb = xsrc + (size_t)b * Ns * 32 + c4 * 4;
            for (int j = 0; j < len; j += 8) {
                int4 sw0 = *(const int4*)(ce + j);
                int4 sw1 = *(const int4*)(ce + j + 4);
                int sea = sw0.x;
                int se1 = (j + 1 < len) ? sw0.y : sea;
                int se2 = (j + 2 < len) ? sw0.z : sea;
                int se3 = (j + 3 < len) ? sw0.w : sea;
                int se4 = (j + 4 < len) ? sw1.x : sea;
                int se5 = (j + 5 < len) ? sw1.y : sea;
                int se6 = (j + 6 < len) ? sw1.z : sea;
                int se7 = (j + 7 < len) ? sw1.w : sea;
                float4 v0 = *(const float4*)(xsb + (size_t)(sea & ~31));
                float4 v1 = *(const float4*)(xsb + (size_t)(se1 & ~31));
                float4 v2 = *(const float4*)(xsb + (size_t)(se2 & ~31));
                float4 v3 = *(const float4*)(xsb + (size_t)(se3 & ~31));
                float4 v4 = *(const float4*)(xsb + (size_t)(se4 & ~31));
                float4 v5 = *(const float4*)(xsb + (size_t)(se5 & ~31));
                float4 v6 = *(const float4*)(xsb + (size_t)(se6 & ~31));
                float4 v7 = *(const float4*)(xsb + (size_t)(se7 & ~31));
#define MINGRP(se, v)  { int* mr = &smxi[((se) & 31) * 4 + b][c4 * 4]; \
                atomicMin(&mr[0], f2ord((v).x)); atomicMin(&mr[1], f2ord((v).y)); \
                atomicMin(&mr[2], f2ord((v).z)); atomicMin(&mr[3], f2ord((v).w)); }
                MINGRP(sea, v0) MINGRP(se1, v1) MINGRP(se2, v2) MINGRP(se3, v3)
                MINGRP(se4, v4) MINGRP(se5, v5) MINGRP(se6, v6) MINGRP(se7, v7)
            }
        } else if (scin == 4) {
            const float* xr = sraw + (size_t)b * Ns * 4;
            float4 w0 = *(const float4*)(sW +  0 + c4 * 4);
            float4 w1 = *(const float4*)(sW + 32 + c4 * 4);
            float4 w2 = *(const float4*)(sW + 64 + c4 * 4);
            float4 w3 = *(const float4*)(sW + 96 + c4 * 4);
            for (int j = 0; j < len; j += 8) {
                int4 sw0 = *(const int4*)(ce + j);
                int4 sw1 = *(const int4*)(ce + j + 4);
                int sea = sw0.x;
                int se1 = (j + 1 < len) ? sw0.y : sea;
                int se2 = (j + 2 < len) ? sw0.z : sea;
                int se3 = (j + 3 < len) ? sw0.w : sea;
                int se4 = (j + 4 < len) ? sw1.x : sea;
                int se5 = (j + 5 < len) ? sw1.y : sea;
                int se6 = (j + 6 < len) ? sw1.z : sea;
                int se7 = (j + 7 < len) ? sw1.w : sea;
                float4 r0 = *(const float4*)(xr + (size_t)(sea >> 5) * 4);
                float4 r1 = *(const float4*)(xr + (size_t)(se1 >> 5) * 4);
                float4 r2 = *(const float4*)(xr + (size_t)(se2 >> 5) * 4);
                float4 r3 = *(const float4*)(xr + (size_t)(se3 >> 5) * 4);
                float4 r4 = *(const float4*)(xr + (size_t)(se4 >> 5) * 4);
                float4 r5 = *(const float4*)(xr + (size_t)(se5 >> 5) * 4);
                float4 r6 = *(const float4*)(xr + (size_t)(se6 >> 5) * 4);
                float4 r7 = *(const float4*)(xr + (size_t)(se7 >> 5) * 4);
// pre-bias pre-activation min (bias edge-invariant, lrelu monotone ->
// both applied once in phase 2)
#define CMIN4(se, rr) { \
    float vx = fmaf((rr).w, w3.x, fmaf((rr).z, w2.x, fmaf((rr).y, w1.x, (rr).x * w0.x))); \
    float vy = fmaf((rr).w, w3.y, fmaf((rr).z, w2.y, fmaf((rr).y, w1.y, (rr).x * w0.y))); \
    float vz = fmaf((rr).w, w3.z, fmaf((rr).z, w2.z, fmaf((rr).y, w1.z, (rr).x * w0.z))); \
    float vw = fmaf((rr).w, w3.w, fmaf((rr).z, w2.w, fmaf((rr).y, w1.w, (rr).x * w0.w))); \
    int* mr = &smxi[((se) & 31) * 4 + b][c4 * 4]; \
    atomicMin(&mr[0], f2ord(vx)); atomicMin(&mr[1], f2ord(vy)); \
    atomicMin(&mr[2], f2ord(vz)); atomicMin(&mr[3], f2ord(vw)); }
                CMIN4(sea, r0) CMIN4(se1, r1) CMIN4(se2, r2) CMIN4(se3, r3)
                CMIN4(se4, r4) CMIN4(se5, r5) CMIN4(se6, r6) CMIN4(se7, r7)
            }
        } else {   // scin == 6, 4-deep (payload 24 regs)
            const float* xr = sraw + (size_t)b * Ns * 6;
            float4 w0 = *(const float4*)(sW +   0 + c4 * 4);
            float4 w1 = *(const float4*)(sW +  32 + c4 * 4);
            float4 w2 = *(const float4*)(sW +  64 + c4 * 4);
            float4 w3 = *(const float4*)(sW +  96 + c4 * 4);
            float4 w4 = *(const float4*)(sW + 128 + c4 * 4);
            float4 w5 = *(const float4*)(sW + 160 + c4 * 4);
            for (int j = 0; j < len; j += 4) {
                int4 sw0 = *(const int4*)(ce + j);
                int sea = sw0.x;
                int se1 = (j + 1 < len) ? sw0.y : sea;
                int se2 = (j + 2 < len) ? sw0.z : sea;
                int se3 = (j + 3 < len) ? sw0.w : sea;
                const float* p0 = xr + (size_t)(sea >> 5) * 6;
                const float* p1 = xr + (size_t)(se1 >> 5) * 6;
                const float* p2 = xr + (size_t)(se2 >> 5) * 6;
                const float* p3 = xr + (size_t)(se3 >> 5) * 6;
                float2 a0 = *(const float2*)p0, m0 = *(const float2*)(p0 + 2), z0 = *(const float2*)(p0 + 4);
                float2 a1 = *(const float2*)p1, m1 = *(const float2*)(p1 + 2), z1 = *(const float2*)(p1 + 4);
                float2 a2 = *(const float2*)p2, m2 = *(const float2*)(p2 + 2), z2 = *(const float2*)(p2 + 4);
                float2 a3 = *(const float2*)p3, m3 = *(const float2*)(p3 + 2), z3 = *(const float2*)(p3 + 4);
#define CMIN6(se, A, M, Z) { \
    float vx = fmaf((Z).y, w5.x, fmaf((Z).x, w4.x, fmaf((M).y, w3.x, fmaf((M).x, w2.x, fmaf((A).y, w1.x, (A).x * w0.x))))); \
    float vy = fmaf((Z).y, w5.y, fmaf((Z).x, w4.y, fmaf((M).y, w3.y, fmaf((M).x, w2.y, fmaf((A).y, w1.y, (A).x * w0.y))))); \
    float vz = fmaf((Z).y, w5.z, fmaf((Z).x, w4.z, fmaf((M).y, w3.z, fmaf((M).x, w2.z, fmaf((A).y, w1.z, (A).x * w0.z))))); \
    float vw = fmaf((Z).y, w5.w, fmaf((Z).x, w4.w, fmaf((M).y, w3.w, fmaf((M).x, w2.w, fmaf((A).y, w1.w, (A).x * w0.w))))); \
    int* mr = &smxi[((se) & 31) * 4 + b][c4 * 4]; \
    atomicMin(&mr[0], f2ord(vx)); atomicMin(&mr[1], f2ord(vy)); \
    atomicMin(&mr[2], f2ord(vz)); atomicMin(&mr[3], f2ord(vw)); }
                CMIN6(sea, a0, m0, z0) CMIN6(se1, a1, m1, z1)
                CMIN6(se2, a2, m2, z2) CMIN6(se3, a3, m3, z3)
            }
        }
    }
    __syncthreads();

    // phase 2: out = xd + lrelu([xd|mx] @ W + bias)
    bool has = (smxi[r][0] != 0x7FFFFFFF);   // per-node all-or-nothing
    bool post = (scin != 0);                 // inline paths minned pre-bias/act
    float mx[32];
#pragma unroll
    for (int q = 0; q < 32; ++q) {
        float v = ord2f(smxi[r][q]);
        if (post) { v = v + sb[q]; v = LRELU(v); }   // sb[q] uniform -> s_load
        mx[q] = has ? (xd[q] - v) : 0.0f;
    }
    const float* Wc = W + c0;
    float acc[16];
#pragma unroll
    for (int jj = 0; jj < 16; ++jj) acc[jj] = bias[c0 + jj];
#pragma unroll
    for (int k = 0; k < 64; ++k) {
        float hk = (k < 32) ? xd[k] : mx[k - 32];   // resolved at unroll time
        const float4* wr = (const float4*)(Wc + k * 32);
        float4 q0 = wr[0], q1 = wr[1], q2 = wr[2], q3 = wr[3];
        acc[0]  = fmaf(hk, q0.x, acc[0]);  acc[1]  = fmaf(hk, q0.y, acc[1]);
        acc[2]  = fmaf(hk, q0.z, acc[2]);  acc[3]  = fmaf(hk, q0.w, acc[3]);
        acc[4]  = fmaf(hk, q1.x, acc[4]);  acc[5]  = fmaf(hk, q1.y, acc[5]);
        acc[6]  = fmaf(hk, q1.z, acc[6]);  acc[7]  = fmaf(hk, q1.w, acc[7]);
        acc[8]  = fmaf(hk, q2.x, acc[8]);  acc[9]  = fmaf(hk, q2.y, acc[9]);
        acc[10] = fmaf(hk, q2.z, acc[10]); acc[11] = fmaf(hk, q2.w, acc[11]);
        acc[12] = fmaf(hk, q3.x, acc[12]); acc[13] = fmaf(hk, q3.y, acc[13]);
        acc[14] = fmaf(hk, q3.z, acc[14]); acc[15] = fmaf(hk, q3.w, acc[15]);
    }
    // residual from registers (c0 is wave-uniform 0 or 16)
    float xr2[16];
#pragma unroll
    for (int i = 0; i < 16; ++i) xr2[i] = (c0 == 0) ? xd[i] : xd[16 + i];
    float* op = out + ((size_t)b2 * Nd + d) * 32 + c0;
#pragma unroll
    for (int q = 0; q < 4; ++q) {
        float4 o;
        float a0 = acc[4*q], a1 = acc[4*q+1], a2 = acc[4*q+2], a3 = acc[4*q+3];
        o.x = xr2[4*q]   + LRELU(a0); o.y = xr2[4*q+1] + LRELU(a1);
        o.z = xr2[4*q+2] + LRELU(a2); o.w = xr2[4*q+3] + LRELU(a3);
        ((float4*)op)[q] = o;
    }
}

extern "C" void kernel_launch(void* const* d_in, const int* in_sizes, int n_in,
                              void* d_out, int out_size, void* d_ws, size_t ws_size,
                              hipStream_t stream) {
    const float* x_f = (const float*)d_in[0];
    const float* x_e = (const float*)d_in[1];
    const float* x_v = (const float*)d_in[2];
    // d_in[3] = index_id (identity arange) — unused
    const int* fe = (const int*)d_in[4];
    const int* ev = (const int*)d_in[5];
    const int* ff = (const int*)d_in[6];
    const int* ef = (const int*)d_in[7];
    const int* ve = (const int*)d_in[8];
    const float* Wf = (const float*)d_in[9];
    const float* bf = (const float*)d_in[10];
    const float* We = (const float*)d_in[11];
    const float* be = (const float*)d_in[12];
    const float* Wv = (const float*)d_in[13];
    const float* bv = (const float*)d_in[14];
    const float* W_f2e = (const float*)d_in[15];
    const float* b_f2e = (const float*)d_in[16];
    const float* W_e2v = (const float*)d_in[17];
    const float* b_e2v = (const float*)d_in[18];
    const float* W_ff  = (const float*)d_in[19];
    const float* b_ff  = (const float*)d_in[20];
    const float* W_e2f = (const float*)d_in[21];
    const float* b_e2f = (const float*)d_in[22];
    const float* W_v2e = (const float*)d_in[23];
    const float* b_v2e = (const float*)d_in[24];

    const int B = 4, Nf = 40000, Ne = 80000, Nv = 40000;
    const int NFC = B * Nf * 32;
    const int NEC = B * Ne * 32;
    const int CUR_TOTAL = 70016;            // 8750*8 cursors (padded)
    const int SLOT_TOTAL = 8750 * 512;      // 8 shards * 64 slots per bucket
    const int INT_WORDS = CUR_TOTAL + SLOT_TOTAL;

    float* oxf = (float*)d_out;        // xf1 then final xf
    float* oxe = oxf + NFC;            // final xe
    float* oxv = oxe + NEC;            // final xv (written once, by E2V)

    // Plan A (merged epilogue) routes xe1 through ws so E2F and V2E can run
    // in ONE dispatch (removes the xe1 read/overwrite anti-dependence).
    size_t needA = (size_t)NEC * 4 + (size_t)INT_WORDS * 4;
    bool merged = ws_size >= needA;

    float* ws  = (float*)d_ws;
    float* xe1 = merged ? ws : oxe;    // where F2E writes xe1
    // int area: cur[70016] | slots[4480000]
    int* cur   = (int*)(merged ? (ws + NEC) : ws);
    int* slots = cur + CUR_TOTAL;

    // zero append cursors (280 KB, stream-ordered, graph-capture-safe)
    hipMemsetAsync(cur, 0, (size_t)CUR_TOTAL * 4, stream);

    // edge-append only (no linear stage — convs inline it at point of use)
    prep<<<3438, 256, 0, stream>>>(fe, ev, ff, ef, ve, cur, slots);

    // per-graph cursor/slot pointers (buckets: 2500,1250,1250,1250,2500)
    const int* cu_f2e = cur;            const int* sl_f2e = slots;
    const int* cu_e2v = cur + 2500*8;   const int* sl_e2v = slots + (size_t)2500*512;
    const int* cu_ff  = cur + 3750*8;   const int* sl_ff  = slots + (size_t)3750*512;
    const int* cu_e2f = cur + 5000*8;   const int* sl_e2f = slots + (size_t)5000*512;
    const int* cu_v2e = cur + 6250*8;   const int* sl_v2e = slots + (size_t)6250*512;

    // Launch 1: F2E + E2V + FF (mutually independent), 32 nodes/block.
    // All src and dst linears computed inline from raw inputs.
    {
        ConvJobs j;
        j.e[0] = {nullptr, nullptr, cu_f2e, sl_f2e, W_f2e, b_f2e, xe1,
                  x_f, Wf, bf, 4,  x_e, We, be, 6,  Nf, Ne, 0};
        j.e[1] = {nullptr, nullptr, cu_e2v, sl_e2v, W_e2v, b_e2v, oxv,
                  x_e, We, be, 6,  x_v, Wv, bv, 3,  Ne, Nv, 2500};
        j.e[2] = {nullptr, nullptr, cu_ff,  sl_ff,  W_ff,  b_ff,  oxf,
                  x_f, Wf, bf, 4,  x_f, Wf, bf, 4,  Nf, Nf, 3750};
        conv_fused<<<5000, 256, 0, stream>>>(j);
    }
    if (merged) {
        // Launch 2: E2F (1250) + V2E (2500) in one dispatch, materialized IO.
        ConvJobs j;
        j.e[0] = {xe1, oxf, cu_e2f, sl_e2f, W_e2f, b_e2f, oxf,
                  nullptr, nullptr, nullptr, 0, nullptr, nullptr, nullptr, 0,
                  Ne, Nf, 0};
        j.e[1] = {oxv, xe1, cu_v2e, sl_v2e, W_v2e, b_v2e, oxe,
                  nullptr, nullptr, nullptr, 0, nullptr, nullptr, nullptr, 0,
                  Nv, Ne, 1250};
        j.e[2] = j.e[0]; j.e[2].blkStart = 0x7FFFFFFF;
        conv_fused<<<3750, 256, 0, stream>>>(j);
    } else {
        // Plan B: serialized epilogue (xe1 lives in oxe, in-place V2E)
        {
            ConvJobs j;
            j.e[0] = {oxe, oxf, cu_e2f, sl_e2f, W_e2f, b_e2f, oxf,
                      nullptr, nullptr, nullptr, 0, nullptr, nullptr, nullptr, 0,
                      Ne, Nf, 0};
            j.e[1] = j.e[0]; j.e[1].blkStart = 0x7FFFFFFF;
            j.e[2] = j.e[0]; j.e[2].blkStart = 0x7FFFFFFF;
            conv_fused<<<1250, 256, 0, stream>>>(j);
        }
        {
            ConvJobs j;
            j.e[0] = {oxv, oxe, cu_v2e, sl_v2e, W_v2e, b_v2e, oxe,
                      nullptr, nullptr, nullptr, 0, nullptr, nullptr, nullptr, 0,
                      Nv, Ne, 0};
            j.e[1] = j.e[0]; j.e[1].blkStart = 0x7FFFFFFF;
            j.e[2] = j.e[0]; j.e[2].blkStart = 0x7FFFFFFF;
            conv_fused<<<2500, 256, 0, stream>>>(j);
        }
    }
}

// Round 17
// 329.767 us; speedup vs baseline: 1.5921x; 1.0460x over previous
//
#include <hip/hip_runtime.h>
#include <float.h>

#define LRELU(v) ((v) > 0.0f ? (v) : 0.01f * (v))

// ---------------- prep: edge append ONLY ----------------
// Input linears are never materialized: conv computes them at point-of-use
// from raw inputs (x_f 2.56MB, x_e 7.7MB, x_v 1.9MB — L2-resident; R11
// measured FETCH 159->63MB). Sharded bucket append — buckets = 32
// consecutive dst nodes, 8 shards/bucket x 64 slots. Shard by edge index
// (idx&7) keeps per-cursor atomic chains ~Poisson(24) worst (R5 lesson:
// 180-400-deep chains = 156us death). Slot packs (src<<5)|(dst&31).
//   g: 0=F2E 1=E2V 2=FF 3=E2F 4=V2E
//   E:       160000,160000,240000,160000,160000 (total 880000)
//   buckets: 2500,1250,1250,1250,2500  bOff: 0,2500,3750,5000,6250 (tot 8750)
__global__ void prep(const int* __restrict__ e0, const int* __restrict__ e1,
                     const int* __restrict__ e2, const int* __restrict__ e3,
                     const int* __restrict__ e4, int* __restrict__ cur,
                     int* __restrict__ slots) {
    int idx = blockIdx.x * 256 + threadIdx.x;
    if (idx >= 880000) return;
    const int cum[6]  = {0, 160000, 320000, 560000, 720000, 880000};
    const int bOff[5] = {0, 2500, 3750, 5000, 6250};
    const int Eg[5]   = {160000, 160000, 240000, 160000, 160000};
    const int* eds[5] = {e0, e1, e2, e3, e4};
    int g = 0;
#pragma unroll
    for (int k = 1; k < 5; ++k) g += (idx >= cum[k]);
    int e = idx - cum[g];
    int s = eds[g][e];
    int d = eds[g][Eg[g] + e];
    int cbase = (bOff[g] + (d >> 5)) * 8 + (idx & 7);
    int c = atomicAdd(&cur[cbase], 1);
    if (c < 64) slots[(size_t)cbase * 64 + c] = (s << 5) | (d & 31);
}

// ---------------- fused conv ----------------
struct ConvJob {
    const float* xsrc; const float* xdst;     // materialized paths (cin==0)
    const int* cur; const int* slots;         // shard cursors + slot pool
    const float* W; const float* bias; float* out;
    const float* sraw; const float* sW; const float* sb; int scin; // src-inline
    const float* draw; const float* dW; const float* db; int dcin; // dst-inline
    int Ns; int Nd; int blkStart;
};
struct ConvJobs { ConvJob e[3]; };

// 32 dst nodes / block of 256 threads. TWO barriers total.
// R17: NATIVE FLOAT LDS MIN — __hip_atomic_fetch_min(float*, relaxed,
// workgroup scope) lowers to ds_min_f32, so the f2ord/ord2f int-ordering
// maps (≈12 VALU/slot-lane in phase 1 + 32 unmaps/thread in phase 2) are
// deleted. Sentinel = +INF (0x7F800000), unreachable from finite inputs.
// R15 LESSON: hot-loop input pointers stay const (write-then-read of slots
// killed aliasing -> 215us); tail-clamp selects stay.
// VGPR CLIFF (R13/R14): waves/CU halve at VGPR=64; R14/R16 land exactly 64
// via bias-after-min -> 39% occ. NEVER force the tier with launch_bounds
// (R13: forced 32 -> total scratch spill, 855MB writes, 431us).
// BIAS-AFTER-MIN + MIN-BEFORE-LRELU (R12/R14, verified): bias is
// edge-invariant and lrelu strictly monotone -> min_e lrelu(Wx_e+b)
// = lrelu(min_e(Wx_e) + b). Inline paths min raw W·x; phase 2 applies
// +sb and lrelu once per (node,ch). scin==0 sources are final features.
// Phase 1: 8 edge-lane groups (32 threads, one (b,c4) per lane); group el
//          walks shard el.
//          scin==0: 8-deep float4 gather of materialized 128B rows.
//          scin==4: 8-deep float4 raw gather (16B rows) + FMA tree.
//          scin==6: 4-deep, 3x float2 raw loads (24B rows alternate 16B/8B
//                   alignment — float4 unsafe) + FMA tree.
//          Tail slots clamp to slot 0; min is idempotent. smxf row stride
//          33 floats: bank = (4*dl+b+4*c4+i)%32 -> conflict-free (measured 0).
// Phase 2: one h-row per lane (wave w: rows (w&1)*64+lane, channel half
//          (w>>1)*16, wave-uniform via readfirstlane). Residual from xd
//          registers. Empty nodes keep the +INF sentinel.
#define FMIN_LDS(p, v) __hip_atomic_fetch_min((p), (v), __ATOMIC_RELAXED, \
                                              __HIP_MEMORY_SCOPE_WORKGROUP)
__global__ __launch_bounds__(256, 1)
void conv_fused(ConvJobs jobs) {
    __shared__ float smxf[128][33];  // [node_local*4+b][c] float mins; 132B rows
    int t = threadIdx.x;
    int bid = blockIdx.x;
    int g = (bid >= jobs.e[2].blkStart) ? 2 : (bid >= jobs.e[1].blkStart) ? 1 : 0;
    const float* xsrc  = jobs.e[g].xsrc;
    const float* xdst  = jobs.e[g].xdst;
    const int*   cur   = jobs.e[g].cur;
    const int*   slots = jobs.e[g].slots;
    const float* W     = jobs.e[g].W;
    const float* bias  = jobs.e[g].bias;
    float*       out   = jobs.e[g].out;
    const float* sraw  = jobs.e[g].sraw;
    const float* sW    = jobs.e[g].sW;
    const float* sb    = jobs.e[g].sb;
    int scin           = jobs.e[g].scin;
    const float* draw  = jobs.e[g].draw;
    const float* dW    = jobs.e[g].dW;
    const float* db    = jobs.e[g].db;
    int dcin           = jobs.e[g].dcin;
    int Ns = jobs.e[g].Ns, Nd = jobs.e[g].Nd;
    int lb = bid - jobs.e[g].blkStart;
    int base = lb * 32;

    for (int i = t; i < 128 * 33; i += 256) ((int*)smxf)[i] = 0x7F800000; // +INF
    __syncthreads();

    // phase 0: phase-2 row mapping + xd (load or inline-compute)
    int w    = t >> 6;
    int lane = t & 63;
    int r    = (w & 1) * 64 + lane;                       // h-row 0..127
    int c0   = __builtin_amdgcn_readfirstlane((w >> 1) * 16);  // wave-uniform
    int nl = r >> 2, b2 = r & 3;
    int d  = base + nl;
    float xd[32];
    if (dcin > 0) {
        // xd = lrelu(draw_row @ dW + db); dW/db loads are uniform
#pragma unroll
        for (int c = 0; c < 32; ++c) xd[c] = db[c];
        const float* xrp = draw + ((size_t)b2 * Nd + d) * dcin;
        for (int k = 0; k < dcin; ++k) {
            float xrk = xrp[k];
            const float* wk = dW + k * 32;
#pragma unroll
            for (int c = 0; c < 32; ++c) xd[c] = fmaf(xrk, wk[c], xd[c]);
        }
#pragma unroll
        for (int c = 0; c < 32; ++c) xd[c] = LRELU(xd[c]);
    } else {
        const float* xdp = xdst + ((size_t)b2 * Nd + d) * 32;
#pragma unroll
        for (int q = 0; q < 8; ++q) {
            float4 v = ((const float4*)xdp)[q];
            xd[4*q] = v.x; xd[4*q+1] = v.y; xd[4*q+2] = v.z; xd[4*q+3] = v.w;
        }
    }

    // phase 1: shard-per-group pipelined gathers + LDS float atomic min
    {
        int c4 = t & 7;            // channel quad
        int b  = (t >> 3) & 3;
        int el = t >> 5;           // shard id 0..7
        int len = cur[lb * 8 + el];
        len = len > 64 ? 64 : len;
        const int* ce = slots + (size_t)(lb * 8 + el) * 64;
        if (scin == 0) {
            const float* xsb = xsrc + (size_t)b * Ns * 32 + c4 * 4;
            for (int j = 0; j < len; j += 8) {
                int4 sw0 = *(const int4*)(ce + j);
                int4 sw1 = *(const int4*)(ce + j + 4);
                int sea = sw0.x;
                int se1 = (j + 1 < len) ? sw0.y : sea;
                int se2 = (j + 2 < len) ? sw0.z : sea;
                int se3 = (j + 3 < len) ? sw0.w : sea;
                int se4 = (j + 4 < len) ? sw1.x : sea;
                int se5 = (j + 5 < len) ? sw1.y : sea;
                int se6 = (j + 6 < len) ? sw1.z : sea;
                int se7 = (j + 7 < len) ? sw1.w : sea;
                float4 v0 = *(const float4*)(xsb + (size_t)(sea & ~31));
                float4 v1 = *(const float4*)(xsb + (size_t)(se1 & ~31));
                float4 v2 = *(const float4*)(xsb + (size_t)(se2 & ~31));
                float4 v3 = *(const float4*)(xsb + (size_t)(se3 & ~31));
                float4 v4 = *(const float4*)(xsb + (size_t)(se4 & ~31));
                float4 v5 = *(const float4*)(xsb + (size_t)(se5 & ~31));
                float4 v6 = *(const float4*)(xsb + (size_t)(se6 & ~31));
                float4 v7 = *(const float4*)(xsb + (size_t)(se7 & ~31));
#define MINGRP(se, v)  { float* mr = &smxf[((se) & 31) * 4 + b][c4 * 4]; \
                FMIN_LDS(&mr[0], (v).x); FMIN_LDS(&mr[1], (v).y); \
                FMIN_LDS(&mr[2], (v).z); FMIN_LDS(&mr[3], (v).w); }
                MINGRP(sea, v0) MINGRP(se1, v1) MINGRP(se2, v2) MINGRP(se3, v3)
                MINGRP(se4, v4) MINGRP(se5, v5) MINGRP(se6, v6) MINGRP(se7, v7)
            }
        } else if (scin == 4) {
            const float* xr = sraw + (size_t)b * Ns * 4;
            float4 w0 = *(const float4*)(sW +  0 + c4 * 4);
            float4 w1 = *(const float4*)(sW + 32 + c4 * 4);
            float4 w2 = *(const float4*)(sW + 64 + c4 * 4);
            float4 w3 = *(const float4*)(sW + 96 + c4 * 4);
            for (int j = 0; j < len; j += 8) {
                int4 sw0 = *(const int4*)(ce + j);
                int4 sw1 = *(const int4*)(ce + j + 4);
                int sea = sw0.x;
                int se1 = (j + 1 < len) ? sw0.y : sea;
                int se2 = (j + 2 < len) ? sw0.z : sea;
                int se3 = (j + 3 < len) ? sw0.w : sea;
                int se4 = (j + 4 < len) ? sw1.x : sea;
                int se5 = (j + 5 < len) ? sw1.y : sea;
                int se6 = (j + 6 < len) ? sw1.z : sea;
                int se7 = (j + 7 < len) ? sw1.w : sea;
                float4 r0 = *(const float4*)(xr + (size_t)(sea >> 5) * 4);
                float4 r1 = *(const float4*)(xr + (size_t)(se1 >> 5) * 4);
                float4 r2 = *(const float4*)(xr + (size_t)(se2 >> 5) * 4);
                float4 r3 = *(const float4*)(xr + (size_t)(se3 >> 5) * 4);
                float4 r4 = *(const float4*)(xr + (size_t)(se4 >> 5) * 4);
                float4 r5 = *(const float4*)(xr + (size_t)(se5 >> 5) * 4);
                float4 r6 = *(const float4*)(xr + (size_t)(se6 >> 5) * 4);
                float4 r7 = *(const float4*)(xr + (size_t)(se7 >> 5) * 4);
// pre-bias pre-activation min (bias edge-invariant, lrelu monotone ->
// both applied once in phase 2)
#define CMIN4(se, rr) { \
    float vx = fmaf((rr).w, w3.x, fmaf((rr).z, w2.x, fmaf((rr).y, w1.x, (rr).x * w0.x))); \
    float vy = fmaf((rr).w, w3.y, fmaf((rr).z, w2.y, fmaf((rr).y, w1.y, (rr).x * w0.y))); \
    float vz = fmaf((rr).w, w3.z, fmaf((rr).z, w2.z, fmaf((rr).y, w1.z, (rr).x * w0.z))); \
    float vw = fmaf((rr).w, w3.w, fmaf((rr).z, w2.w, fmaf((rr).y, w1.w, (rr).x * w0.w))); \
    float* mr = &smxf[((se) & 31) * 4 + b][c4 * 4]; \
    FMIN_LDS(&mr[0], vx); FMIN_LDS(&mr[1], vy); \
    FMIN_LDS(&mr[2], vz); FMIN_LDS(&mr[3], vw); }
                CMIN4(sea, r0) CMIN4(se1, r1) CMIN4(se2, r2) CMIN4(se3, r3)
                CMIN4(se4, r4) CMIN4(se5, r5) CMIN4(se6, r6) CMIN4(se7, r7)
            }
        } else {   // scin == 6, 4-deep (payload 24 regs)
            const float* xr = sraw + (size_t)b * Ns * 6;
            float4 w0 = *(const float4*)(sW +   0 + c4 * 4);
            float4 w1 = *(const float4*)(sW +  32 + c4 * 4);
            float4 w2 = *(const float4*)(sW +  64 + c4 * 4);
            float4 w3 = *(const float4*)(sW +  96 + c4 * 4);
            float4 w4 = *(const float4*)(sW + 128 + c4 * 4);
            float4 w5 = *(const float4*)(sW + 160 + c4 * 4);
            for (int j = 0; j < len; j += 4) {
                int4 sw0 = *(const int4*)(ce + j);
                int sea = sw0.x;
                int se1 = (j + 1 < len) ? sw0.y : sea;
                int se2 = (j + 2 < len) ? sw0.z : sea;
                int se3 = (j + 3 < len) ? sw0.w : sea;
                const float* p0 = xr + (size_t)(sea >> 5) * 6;
                const float* p1 = xr + (size_t)(se1 >> 5) * 6;
                const float* p2 = xr + (size_t)(se2 >> 5) * 6;
                const float* p3 = xr + (size_t)(se3 >> 5) * 6;
                float2 a0 = *(const float2*)p0, m0 = *(const float2*)(p0 + 2), z0 = *(const float2*)(p0 + 4);
                float2 a1 = *(const float2*)p1, m1 = *(const float2*)(p1 + 2), z1 = *(const float2*)(p1 + 4);
                float2 a2 = *(const float2*)p2, m2 = *(const float2*)(p2 + 2), z2 = *(const float2*)(p2 + 4);
                float2 a3 = *(const float2*)p3, m3 = *(const float2*)(p3 + 2), z3 = *(const float2*)(p3 + 4);
#define CMIN6(se, A, M, Z) { \
    float vx = fmaf((Z).y, w5.x, fmaf((Z).x, w4.x, fmaf((M).y, w3.x, fmaf((M).x, w2.x, fmaf((A).y, w1.x, (A).x * w0.x))))); \
    float vy = fmaf((Z).y, w5.y, fmaf((Z).x, w4.y, fmaf((M).y, w3.y, fmaf((M).x, w2.y, fmaf((A).y, w1.y, (A).x * w0.y))))); \
    float vz = fmaf((Z).y, w5.z, fmaf((Z).x, w4.z, fmaf((M).y, w3.z, fmaf((M).x, w2.z, fmaf((A).y, w1.z, (A).x * w0.z))))); \
    float vw = fmaf((Z).y, w5.w, fmaf((Z).x, w4.w, fmaf((M).y, w3.w, fmaf((M).x, w2.w, fmaf((A).y, w1.w, (A).x * w0.w))))); \
    float* mr = &smxf[((se) & 31) * 4 + b][c4 * 4]; \
    FMIN_LDS(&mr[0], vx); FMIN_LDS(&mr[1], vy); \
    FMIN_LDS(&mr[2], vz); FMIN_LDS(&mr[3], vw); }
                CMIN6(sea, a0, m0, z0) CMIN6(se1, a1, m1, z1)
                CMIN6(se2, a2, m2, z2) CMIN6(se3, a3, m3, z3)
            }
        }
    }
    __syncthreads();

    // phase 2: out = xd + lrelu([xd|mx] @ W + bias)
    bool has = (__float_as_int(smxf[r][0]) != 0x7F800000); // per-node all-or-nothing
    bool post = (scin != 0);                 // inline paths minned pre-bias/act
    float mx[32];
#pragma unroll
    for (int q = 0; q < 32; ++q) {
        float v = smxf[r][q];
        if (post) { v = v + sb[q]; v = LRELU(v); }   // sb[q] uniform -> s_load
        mx[q] = has ? (xd[q] - v) : 0.0f;
    }
    const float* Wc = W + c0;
    float acc[16];
#pragma unroll
    for (int jj = 0; jj < 16; ++jj) acc[jj] = bias[c0 + jj];
#pragma unroll
    for (int k = 0; k < 64; ++k) {
        float hk = (k < 32) ? xd[k] : mx[k - 32];   // resolved at unroll time
        const float4* wr = (const float4*)(Wc + k * 32);
        float4 q0 = wr[0], q1 = wr[1], q2 = wr[2], q3 = wr[3];
        acc[0]  = fmaf(hk, q0.x, acc[0]);  acc[1]  = fmaf(hk, q0.y, acc[1]);
        acc[2]  = fmaf(hk, q0.z, acc[2]);  acc[3]  = fmaf(hk, q0.w, acc[3]);
        acc[4]  = fmaf(hk, q1.x, acc[4]);  acc[5]  = fmaf(hk, q1.y, acc[5]);
        acc[6]  = fmaf(hk, q1.z, acc[6]);  acc[7]  = fmaf(hk, q1.w, acc[7]);
        acc[8]  = fmaf(hk, q2.x, acc[8]);  acc[9]  = fmaf(hk, q2.y, acc[9]);
        acc[10] = fmaf(hk, q2.z, acc[10]); acc[11] = fmaf(hk, q2.w, acc[11]);
        acc[12] = fmaf(hk, q3.x, acc[12]); acc[13] = fmaf(hk, q3.y, acc[13]);
        acc[14] = fmaf(hk, q3.z, acc[14]); acc[15] = fmaf(hk, q3.w, acc[15]);
    }
    // residual from registers (c0 is wave-uniform 0 or 16)
    float xr2[16];
#pragma unroll
    for (int i = 0; i < 16; ++i) xr2[i] = (c0 == 0) ? xd[i] : xd[16 + i];
    float* op = out + ((size_t)b2 * Nd + d) * 32 + c0;
#pragma unroll
    for (int q = 0; q < 4; ++q) {
        float4 o;
        float a0 = acc[4*q], a1 = acc[4*q+1], a2 = acc[4*q+2], a3 = acc[4*q+3];
        o.x = xr2[4*q]   + LRELU(a0); o.y = xr2[4*q+1] + LRELU(a1);
        o.z = xr2[4*q+2] + LRELU(a2); o.w = xr2[4*q+3] + LRELU(a3);
        ((float4*)op)[q] = o;
    }
}

extern "C" void kernel_launch(void* const* d_in, const int* in_sizes, int n_in,
                              void* d_out, int out_size, void* d_ws, size_t ws_size,
                              hipStream_t stream) {
    const float* x_f = (const float*)d_in[0];
    const float* x_e = (const float*)d_in[1];
    const float* x_v = (const float*)d_in[2];
    // d_in[3] = index_id (identity arange) — unused
    const int* fe = (const int*)d_in[4];
    const int* ev = (const int*)d_in[5];
    const int* ff = (const int*)d_in[6];
    const int* ef = (const int*)d_in[7];
    const int* ve = (const int*)d_in[8];
    const float* Wf = (const float*)d_in[9];
    const float* bf = (const float*)d_in[10];
    const float* We = (const float*)d_in[11];
    const float* be = (const float*)d_in[12];
    const float* Wv = (const float*)d_in[13];
    const float* bv = (const float*)d_in[14];
    const float* W_f2e = (const float*)d_in[15];
    const float* b_f2e = (const float*)d_in[16];
    const float* W_e2v = (const float*)d_in[17];
    const float* b_e2v = (const float*)d_in[18];
    const float* W_ff  = (const float*)d_in[19];
    const float* b_ff  = (const float*)d_in[20];
    const float* W_e2f = (const float*)d_in[21];
    const float* b_e2f = (const float*)d_in[22];
    const float* W_v2e = (const float*)d_in[23];
    const float* b_v2e = (const float*)d_in[24];

    const int B = 4, Nf = 40000, Ne = 80000, Nv = 40000;
    const int NFC = B * Nf * 32;
    const int NEC = B * Ne * 32;
    const int CUR_TOTAL = 70016;            // 8750*8 cursors (padded)
    const int SLOT_TOTAL = 8750 * 512;      // 8 shards * 64 slots per bucket
    const int INT_WORDS = CUR_TOTAL + SLOT_TOTAL;

    float* oxf = (float*)d_out;        // xf1 then final xf
    float* oxe = oxf + NFC;            // final xe
    float* oxv = oxe + NEC;            // final xv (written once, by E2V)

    // Plan A (merged epilogue) routes xe1 through ws so E2F and V2E can run
    // in ONE dispatch (removes the xe1 read/overwrite anti-dependence).
    size_t needA = (size_t)NEC * 4 + (size_t)INT_WORDS * 4;
    bool merged = ws_size >= needA;

    float* ws  = (float*)d_ws;
    float* xe1 = merged ? ws : oxe;    // where F2E writes xe1
    // int area: cur[70016] | slots[4480000]
    int* cur   = (int*)(merged ? (ws + NEC) : ws);
    int* slots = cur + CUR_TOTAL;

    // zero append cursors (280 KB, stream-ordered, graph-capture-safe)
    hipMemsetAsync(cur, 0, (size_t)CUR_TOTAL * 4, stream);

    // edge-append only (no linear stage — convs inline it at point of use)
    prep<<<3438, 256, 0, stream>>>(fe, ev, ff, ef, ve, cur, slots);

    // per-graph cursor/slot pointers (buckets: 2500,1250,1250,1250,2500)
    const int* cu_f2e = cur;            const int* sl_f2e = slots;
    const int* cu_e2v = cur + 2500*8;   const int* sl_e2v = slots + (size_t)2500*512;
    const int* cu_ff  = cur + 3750*8;   const int* sl_ff  = slots + (size_t)3750*512;
    const int* cu_e2f = cur + 5000*8;   const int* sl_e2f = slots + (size_t)5000*512;
    const int* cu_v2e = cur + 6250*8;   const int* sl_v2e = slots + (size_t)6250*512;

    // Launch 1: F2E + E2V + FF (mutually independent), 32 nodes/block.
    // All src and dst linears computed inline from raw inputs.
    {
        ConvJobs j;
        j.e[0] = {nullptr, nullptr, cu_f2e, sl_f2e, W_f2e, b_f2e, xe1,
                  x_f, Wf, bf, 4,  x_e, We, be, 6,  Nf, Ne, 0};
        j.e[1] = {nullptr, nullptr, cu_e2v, sl_e2v, W_e2v, b_e2v, oxv,
                  x_e, We, be, 6,  x_v, Wv, bv, 3,  Ne, Nv, 2500};
        j.e[2] = {nullptr, nullptr, cu_ff,  sl_ff,  W_ff,  b_ff,  oxf,
                  x_f, Wf, bf, 4,  x_f, Wf, bf, 4,  Nf, Nf, 3750};
        conv_fused<<<5000, 256, 0, stream>>>(j);
    }
    if (merged) {
        // Launch 2: E2F (1250) + V2E (2500) in one dispatch, materialized IO.
        ConvJobs j;
        j.e[0] = {xe1, oxf, cu_e2f, sl_e2f, W_e2f, b_e2f, oxf,
                  nullptr, nullptr, nullptr, 0, nullptr, nullptr, nullptr, 0,
                  Ne, Nf, 0};
        j.e[1] = {oxv, xe1, cu_v2e, sl_v2e, W_v2e, b_v2e, oxe,
                  nullptr, nullptr, nullptr, 0, nullptr, nullptr, nullptr, 0,
                  Nv, Ne, 1250};
        j.e[2] = j.e[0]; j.e[2].blkStart = 0x7FFFFFFF;
        conv_fused<<<3750, 256, 0, stream>>>(j);
    } else {
        // Plan B: serialized epilogue (xe1 lives in oxe, in-place V2E)
        {
            ConvJobs j;
            j.e[0] = {oxe, oxf, cu_e2f, sl_e2f, W_e2f, b_e2f, oxf,
                      nullptr, nullptr, nullptr, 0, nullptr, nullptr, nullptr, 0,
                      Ne, Nf, 0};
            j.e[1] = j.e[0]; j.e[1].blkStart = 0x7FFFFFFF;
            j.e[2] = j.e[0]; j.e[2].blkStart = 0x7FFFFFFF;
            conv_fused<<<1250, 256, 0, stream>>>(j);
        }
        {
            ConvJobs j;
            j.e[0] = {oxv, oxe, cu_v2e, sl_v2e, W_v2e, b_v2e, oxe,
                      nullptr, nullptr, nullptr, 0, nullptr, nullptr, nullptr, 0,
                      Nv, Ne, 0};
            j.e[1] = j.e[0]; j.e[1].blkStart = 0x7FFFFFFF;
            j.e[2] = j.e[0]; j.e[2].blkStart = 0x7FFFFFFF;
            conv_fused<<<2500, 256, 0, stream>>>(j);
        }
    }
}